// Round 4
// baseline (130.755 us; speedup 1.0000x reference)
//
#include <hip/hip_runtime.h>

// Spread: out[b,m] = sum_{j=0..2} x[b,m-j] * W[m,m-j] * (1+bias[m])^p(j,m)
// p = j+1 - max(0, m-(N_IN-1)); terms dropped when m-j outside [0,N_IN).
// (Scan unrolled: column m is touched by steps n=m-2,m-1,m; each touch
//  multiplies previously-accumulated terms by s=1+bias[m] once.)
//
// Layout: thread q owns columns 4q..4q+3 (m<=4095 -> no tail-scale reduction
// in the hot path). x loads: one aligned float4 (x[m0..m0+3]) + one aligned
// float2 left-halo (x[m0-2..m0-1]). Columns 4096/4097 fold into quad 1023,
// reusing its hi.z/hi.w -- zero extra x traffic. Stores: two float2 per quad
// (row stride 4098 ≡ 2 mod 4 floats forbids float4 on odd rows); regular
// stores so L2 write-combines the half-line pairs.

constexpr int N_IN  = 4096;
constexpr int N_OUT = 4098;
constexpr int BATCH = 2048;
constexpr int ROWS  = 16;   // batch rows per thread

typedef float v2f __attribute__((ext_vector_type(2)));
typedef float v4f __attribute__((ext_vector_type(4)));

__global__ __launch_bounds__(256) void spread_fused(
    const float* __restrict__ x, const float* __restrict__ weight,
    const float* __restrict__ bias, float* __restrict__ out) {
  int q  = blockIdx.x * blockDim.x + threadIdx.x;   // 0..1023, exact
  int m0 = q * 4;
  const bool first = (q == 0);
  const bool tail  = (q == 1023);

  // Main coefficients: c[j][k] = W[m,m-j] * s^(j+1), m = m0+k (all m<=4095).
  float c[3][4];
#pragma unroll
  for (int k = 0; k < 4; ++k) {
    int m = m0 + k;
    float s  = 1.0f + bias[m];
    float sp = s;
#pragma unroll
    for (int j = 0; j < 3; ++j) {
      c[j][k] = (m - j >= 0) ? weight[(size_t)m * N_IN + (m - j)] * sp : 0.0f;
      sp *= s;
    }
  }

  // Tail coefficients for columns 4096/4097 (only quad 1023).
  float ct0 = 0.0f, ct1 = 0.0f, ct2 = 0.0f;
  if (tail) {
    float sA = 1.0f + bias[4096];            // m=4096: red=1 -> p = j
    ct0 = weight[(size_t)4096 * N_IN + 4095] * sA;        // j=1, p=1
    ct1 = weight[(size_t)4096 * N_IN + 4094] * sA * sA;   // j=2, p=2
    float sB = 1.0f + bias[4097];            // m=4097: red=2 -> p = j-1
    ct2 = weight[(size_t)4097 * N_IN + 4095] * sB;        // j=2, p=1
  }

  int b0 = blockIdx.y * ROWS;
#pragma unroll
  for (int r = 0; r < ROWS; ++r) {
    int b = b0 + r;
    const float* xrow = x + (size_t)b * N_IN;
    v4f hi = *(const v4f*)(xrow + m0);       // x[m0..m0+3], 16B-aligned
    v2f lo;
    if (first) { lo.x = 0.0f; lo.y = 0.0f; }
    else       { lo = *(const v2f*)(xrow + m0 - 2); }   // x[m0-2..m0-1]

    float o0 = c[0][0] * hi.x + c[1][0] * lo.y + c[2][0] * lo.x;
    float o1 = c[0][1] * hi.y + c[1][1] * hi.x + c[2][1] * lo.y;
    float o2 = c[0][2] * hi.z + c[1][2] * hi.y + c[2][2] * hi.x;
    float o3 = c[0][3] * hi.w + c[1][3] * hi.z + c[2][3] * hi.y;

    float* orow = out + (size_t)b * N_OUT + m0;
    v2f s01; s01.x = o0; s01.y = o1;
    v2f s23; s23.x = o2; s23.y = o3;
    *(v2f*)(orow)     = s01;
    *(v2f*)(orow + 2) = s23;

    if (tail) {                              // cols 4096/4097 from own hi
      v2f st;
      st.x = ct0 * hi.w + ct1 * hi.z;        // x[4095], x[4094]
      st.y = ct2 * hi.w;                     // x[4095]
      *(v2f*)(orow + 4) = st;
    }
  }
}

extern "C" void kernel_launch(void* const* d_in, const int* in_sizes, int n_in,
                              void* d_out, int out_size, void* d_ws, size_t ws_size,
                              hipStream_t stream) {
  const float* x    = (const float*)d_in[0];
  const float* w    = (const float*)d_in[1];
  const float* bias = (const float*)d_in[2];
  float* out = (float*)d_out;

  dim3 grid(4, BATCH / ROWS);                // 4*256 threads = 1024 quads exact
  spread_fused<<<grid, dim3(256), 0, stream>>>(x, w, bias, out);
}